// Round 6
// baseline (799.676 us; speedup 1.0000x reference)
//
#include <hip/hip_runtime.h>
#include <hip/hip_bf16.h>
#include <cstdint>
#include <cstddef>

#define NN 4096
#define NE 65536
#define HD 256

typedef __attribute__((ext_vector_type(4))) float f32x4;
typedef __attribute__((ext_vector_type(16))) float f32x16;
typedef __attribute__((ext_vector_type(8))) __bf16 bf16x8;

static __device__ __forceinline__ float silu_f(float v) {
  return v / (1.f + __expf(-v));
}

// ---------------- weight transpose/convert: f32 [K,N] -> bf16 [N,K] ----------
struct TJob { const float* src; __bf16* dst; int K; int N; };
struct TJobs { TJob j[39]; };

__global__ __launch_bounds__(256) void k_transpose(TJobs jobs) {
  TJob jb = jobs.j[blockIdx.z];
  int k0 = blockIdx.x << 5, n0 = blockIdx.y << 5;
  if (k0 >= jb.K || n0 >= jb.N) return;
  __shared__ float t[32][33];
  int tx = threadIdx.x & 31, ty = threadIdx.x >> 5;
#pragma unroll
  for (int r = ty; r < 32; r += 8)
    t[r][tx] = jb.src[(size_t)(k0 + r) * jb.N + n0 + tx];
  __syncthreads();
#pragma unroll
  for (int r = ty; r < 32; r += 8)
    jb.dst[(size_t)(n0 + r) * jb.K + k0 + tx] = (__bf16)t[tx][r];
}

// ---------------- CSR build ----------------
__global__ __launch_bounds__(256) void k_hist(const int* __restrict__ ei, int* __restrict__ cnt) {
  int e = blockIdx.x * 256 + threadIdx.x;
  atomicAdd(&cnt[ei[e]], 1);
}

__global__ __launch_bounds__(1024) void k_scan(const int* __restrict__ cnt, int* __restrict__ offs,
                                               int* __restrict__ cursor) {
  __shared__ int tmp[1024];
  int tid = threadIdx.x;
  int v[4]; int s = 0;
#pragma unroll
  for (int i = 0; i < 4; i++) { v[i] = cnt[tid * 4 + i]; s += v[i]; }
  tmp[tid] = s;
  __syncthreads();
  for (int o = 1; o < 1024; o <<= 1) {
    int t = (tid >= o) ? tmp[tid - o] : 0;
    __syncthreads();
    tmp[tid] += t;
    __syncthreads();
  }
  int base = (tid > 0) ? tmp[tid - 1] : 0;
#pragma unroll
  for (int i = 0; i < 4; i++) {
    offs[tid * 4 + i] = base; cursor[tid * 4 + i] = base; base += v[i];
  }
  if (tid == 1023) offs[4096] = base;
}

__global__ __launch_bounds__(256) void k_scatter(const int* __restrict__ ei, int* __restrict__ cursor,
                                                 int* __restrict__ elist) {
  int e = blockIdx.x * 256 + threadIdx.x;
  int pos = atomicAdd(&cursor[ei[e]], 1);
  elist[pos] = e;
}

// CSR metadata + dist0 (from initial x) + xc init
__global__ __launch_bounds__(256) void k_csrinit(const int* __restrict__ elist, const int* __restrict__ ei,
                                                 const float* __restrict__ x, int* __restrict__ rowp,
                                                 int* __restrict__ colp, float* __restrict__ d0p,
                                                 float* __restrict__ xc) {
  int i = blockIdx.x * 256 + threadIdx.x;
  if (i < NN * 3) xc[i] = x[i];
  int e = elist[i];
  int r = ei[e], c = ei[NE + e];
  rowp[i] = r; colp[i] = c;
  float dx = x[r * 3 + 0] - x[c * 3 + 0];
  float dy = x[r * 3 + 1] - x[c * 3 + 1];
  float dz = x[r * 3 + 2] - x[c * 3 + 2];
  d0p[i] = dx * dx + dy * dy + dz * dz;
}

// per-block geometry (radial + coord_diff) in CSR order, from current coords
__global__ __launch_bounds__(256) void k_geo(const int* __restrict__ rowp, const int* __restrict__ colp,
                                             const float* __restrict__ x, float* __restrict__ radp,
                                             float* __restrict__ cdp) {
  int i = blockIdx.x * 256 + threadIdx.x;
  int r = rowp[i], c = colp[i];
  float dx = x[r * 3 + 0] - x[c * 3 + 0];
  float dy = x[r * 3 + 1] - x[c * 3 + 1];
  float dz = x[r * 3 + 2] - x[c * 3 + 2];
  float rad = dx * dx + dy * dy + dz * dz;
  radp[i] = rad;
  float inv = 1.f / (sqrtf(rad + 1e-8f) + 1.f);
  cdp[i * 3 + 0] = dx * inv; cdp[i * 3 + 1] = dy * inv; cdp[i * 3 + 2] = dz * inv;
}

__global__ __launch_bounds__(256) void k_embed(const float* __restrict__ h0, const float* __restrict__ W,
                                               const float* __restrict__ b, float* __restrict__ hf,
                                               __bf16* __restrict__ h16) {
  int n = blockIdx.x, c = threadIdx.x;
  float s = b[c];
#pragma unroll
  for (int i = 0; i < 16; i++) s += h0[n * 16 + i] * W[i * 256 + c];
  hf[(size_t)n * HD + c] = s;
  h16[(size_t)n * HD + c] = (__bf16)s;
}

// seg-sum over CSR (m2p CSR-ordered) -> agg16 = bf16(sum/100)
__global__ __launch_bounds__(256) void k_segsum(const __bf16* __restrict__ m2p, const int* __restrict__ offs,
                                                __bf16* __restrict__ agg16) {
  __shared__ float sd[8][256];
  int n = blockIdx.x, t = threadIdx.x;
  int g = t >> 5, l = t & 31;
  int c0 = l << 3;
  float a[8] = {};
  int ib = offs[n], ie = offs[n + 1];
  for (int i = ib + g; i < ie; i += 8) {
    bf16x8 v = *(const bf16x8*)(m2p + (size_t)i * 256 + c0);
#pragma unroll
    for (int j = 0; j < 8; j++) a[j] += (float)v[j];
  }
#pragma unroll
  for (int j = 0; j < 8; j++) sd[g][c0 + j] = a[j];
  __syncthreads();
  float s = 0.f;
#pragma unroll
  for (int j = 0; j < 8; j++) s += sd[j][t];
  agg16[(size_t)n * 256 + t] = (__bf16)(s * 0.01f);
}

__global__ __launch_bounds__(256) void k_xupd(const float* __restrict__ transp, const int* __restrict__ offs,
                                              float* __restrict__ xc) {
  int n = blockIdx.x * 256 + threadIdx.x;
  if (n >= NN) return;
  float a0 = 0.f, a1 = 0.f, a2 = 0.f;
  int i1 = offs[n + 1];
  for (int i = offs[n]; i < i1; i++) {
    a0 += transp[i * 3 + 0]; a1 += transp[i * 3 + 1]; a2 += transp[i * 3 + 2];
  }
  xc[n * 3 + 0] += a0 * 0.01f;
  xc[n * 3 + 1] += a1 * 0.01f;
  xc[n * 3 + 2] += a2 * 0.01f;
}

// final: out_h = hf@out_w + out_b ; out_x = xc
__global__ __launch_bounds__(256) void k_out(const float* __restrict__ hf, const float* __restrict__ W,
                                             const float* __restrict__ b, const float* __restrict__ xc,
                                             float* __restrict__ out) {
  int t = blockIdx.x * 256 + threadIdx.x;
  if (blockIdx.x < 256) {
    int n = t >> 4, j = t & 15;
    float s = b[j];
    for (int c = 0; c < 256; c++) s += hf[(size_t)n * HD + c] * W[c * 16 + j];
    out[n * 16 + j] = s;
  } else {
    int i = t - NN * 16;
    if (i < NN * 3) out[NN * 16 + i] = xc[i];
  }
}

// ---------------- fused edge-block kernel (v5: 32x32 MFMA, register-A) ----------------
// Block = 4 waves x 32 edges = 128 CSR-ordered edges; all 256 output cols per wave.
// A-fragment per-lane in regs: lane -> edge (lane&31), k-half (lane>>5).
// B = W2^T staged GRANULE-MAJOR [4][256][8elem] per 32-k tile, double-buffered (conflict-free).
// acc: 8 x f32x16 (32x32x16 MFMA).  __launch_bounds__(256,2): 256-reg budget, no spill.
// EPI 0: m2p[i][col] = silu(out + b2)  (LDS-restaged coalesced stores)
// EPI 1: trans[i] = cdp[i] * sum_col(silu(out+b2)*w3[col])
template <int EPI>
__global__ __launch_bounds__(256, 2) void k_edgeblk(
    const __bf16* __restrict__ PQ, const int* __restrict__ rowp, const int* __restrict__ colp,
    const float* __restrict__ radp, const float* __restrict__ d0p,
    const float* __restrict__ w1r, const float* __restrict__ w1d, const float* __restrict__ b1,
    const __bf16* __restrict__ Bt, const float* __restrict__ b2,
    __bf16* __restrict__ m2p,
    const float* __restrict__ w3, const float* __restrict__ cdp, float* __restrict__ transp) {
  __shared__ alignas(16) char smem[37888];
  float*  wgt = (float*)smem;                       // [5][256] f32: w1r,w1d,b1,b2,w3
  __bf16* Bs0 = (__bf16*)(smem + 5120);             // [4][256][8] bf16 granule-major, 16 KB
  __bf16* Bs1 = (__bf16*)(smem + 5120 + 16384);     // buffer 1

  const int tid = threadIdx.x;
  const int lane = tid & 63;
  const int w = tid >> 6;          // wave 0..3
  const int l31 = lane & 31;
  const int kh = lane >> 5;        // k-half 0/1
  const int R0 = blockIdx.x * 128;
  const int erow = R0 + w * 32 + l31;

  const __bf16* pB = PQ + (size_t)rowp[erow] * 512 + kh * 8;
  const __bf16* qB = PQ + (size_t)colp[erow] * 512 + 256 + kh * 8;
  const float rad = radp[erow], dd0 = d0p[erow];

  // stage weights (broadcast-read later)
  wgt[tid]       = w1r[tid];
  wgt[256 + tid] = w1d[tid];
  wgt[512 + tid] = b1[tid];
  wgt[768 + tid] = b2[tid];
  if (EPI == 1) wgt[1024 + tid] = w3[tid];

  // B staging map: lane -> rows (w*64 + (lane&15) + 16*i), granule sg = lane>>4
  const int sn0 = w * 64 + (lane & 15);
  const int sg = lane >> 4;

  // prologue: B tile 0 + A step 0
  uint4 rb[4];
#pragma unroll
  for (int i = 0; i < 4; i++)
    rb[i] = *(const uint4*)(Bt + (size_t)(sn0 + 16 * i) * 256 + sg * 8);
  bf16x8 p0c = *(const bf16x8*)(pB);
  bf16x8 p1c = *(const bf16x8*)(pB + 16);
  bf16x8 q0c = *(const bf16x8*)(qB);
  bf16x8 q1c = *(const bf16x8*)(qB + 16);
#pragma unroll
  for (int i = 0; i < 4; i++)
    *(uint4*)&Bs0[sg * 2048 + (sn0 + 16 * i) * 8] = rb[i];
  __syncthreads();

  f32x16 acc[8] = {};

#pragma unroll
  for (int t = 0; t < 8; t++) {
    const __bf16* Bc = (t & 1) ? Bs1 : Bs0;
    __bf16*       Bn = (t & 1) ? Bs0 : Bs1;
    bf16x8 p0n, p1n, q0n, q1n;
    if (t < 7) {   // issue next-tile loads early; latency hides under silu+MFMA
      int kt = (t + 1) * 32;
#pragma unroll
      for (int i = 0; i < 4; i++)
        rb[i] = *(const uint4*)(Bt + (size_t)(sn0 + 16 * i) * 256 + kt + sg * 8);
      p0n = *(const bf16x8*)(pB + kt);
      p1n = *(const bf16x8*)(pB + kt + 16);
      q0n = *(const bf16x8*)(qB + kt);
      q1n = *(const bf16x8*)(qB + kt + 16);
    }
#pragma unroll
    for (int s = 0; s < 2; s++) {    // two k16 substeps
      const int k0 = t * 32 + s * 16 + kh * 8;
      f32x4 wrA = *(const f32x4*)&wgt[k0],       wrB = *(const f32x4*)&wgt[k0 + 4];
      f32x4 wdA = *(const f32x4*)&wgt[256 + k0], wdB = *(const f32x4*)&wgt[256 + k0 + 4];
      f32x4 bbA = *(const f32x4*)&wgt[512 + k0], bbB = *(const f32x4*)&wgt[512 + k0 + 4];
      bf16x8 pv = s ? p1c : p0c;
      bf16x8 qv = s ? q1c : q0c;
      bf16x8 af;
#pragma unroll
      for (int j = 0; j < 4; j++)
        af[j] = (__bf16)silu_f((float)pv[j] + (float)qv[j] + rad * wrA[j] + dd0 * wdA[j] + bbA[j]);
#pragma unroll
      for (int j = 0; j < 4; j++)
        af[4 + j] = (__bf16)silu_f((float)pv[4 + j] + (float)qv[4 + j] + rad * wrB[j] + dd0 * wdB[j] + bbB[j]);
      const int gb = (s * 2 + kh) * 2048;
#pragma unroll
      for (int fn = 0; fn < 8; fn++) {
        bf16x8 bfv = *(const bf16x8*)&Bc[gb + (fn * 32 + l31) * 8];
        acc[fn] = __builtin_amdgcn_mfma_f32_32x32x16_bf16(af, bfv, acc[fn], 0, 0, 0);
      }
    }
    if (t < 7) {
#pragma unroll
      for (int i = 0; i < 4; i++)
        *(uint4*)&Bn[sg * 2048 + (sn0 + 16 * i) * 8] = rb[i];
      p0c = p0n; p1c = p1n; q0c = q0n; q1c = q1n;
    }
    __syncthreads();
  }

  // ---- epilogue ----
  // C layout: col = fn*32 + l31, row_local = (reg&3) + 8*(reg>>2) + 4*kh
  if (EPI == 0) {
    __bf16* ep = (__bf16*)(smem + 5120) + w * 2112;   // per-wave [8][264]
#pragma unroll
    for (int p = 0; p < 4; p++) {   // rows p*8 .. p*8+7
#pragma unroll
      for (int fn = 0; fn < 8; fn++) {
        int col = fn * 32 + l31;
        float bv = wgt[768 + col];
#pragma unroll
        for (int jj = 0; jj < 4; jj++)
          ep[(jj + 4 * kh) * 264 + col] = (__bf16)silu_f(acc[fn][p * 4 + jj] + bv);
      }
      __syncthreads();
#pragma unroll
      for (int i = 0; i < 4; i++) {
        int row = i * 2 + kh;
        uint4 v = *(const uint4*)&ep[row * 264 + l31 * 8];
        *(uint4*)(m2p + (size_t)(R0 + w * 32 + p * 8 + row) * 256 + l31 * 8) = v;
      }
      __syncthreads();
    }
  } else {
    float s[16];
#pragma unroll
    for (int j = 0; j < 16; j++) s[j] = 0.f;
#pragma unroll
    for (int fn = 0; fn < 8; fn++) {
      int col = fn * 32 + l31;
      float bv = wgt[768 + col], wv = wgt[1024 + col];
#pragma unroll
      for (int j = 0; j < 16; j++)
        s[j] += silu_f(acc[fn][j] + bv) * wv;
    }
#pragma unroll
    for (int off = 1; off < 32; off <<= 1)
#pragma unroll
      for (int j = 0; j < 16; j++)
        s[j] += __shfl_xor(s[j], off, 64);
    // row for reg j: (j&3) + 8*(j>>2) + 4*kh ; lane l31==j (in each half) writes it
#pragma unroll
    for (int j = 0; j < 16; j++) {
      if (l31 == j) {
        int row = (j & 3) + 8 * (j >> 2) + 4 * kh;
        size_t i = (size_t)R0 + w * 32 + row;
        transp[i * 3 + 0] = cdp[i * 3 + 0] * s[j];
        transp[i * 3 + 1] = cdp[i * 3 + 1] * s[j];
        transp[i * 3 + 2] = cdp[i * 3 + 2] * s[j];
      }
    }
  }
}

// ---------------- 64x64 MFMA GEMM, 2-phase double-buffered ----------------
// C = epi(A[M,K] @ Bt[N,K]^T + bias).
// SPLIT=1: logical K=512, A-rows = [A(256) || A2(256)], both row-stride 256.
// EPI: 1 silu->bf16, 2 residual f32+=v & bf16 out, 4 plain bf16
template <int EPI, int SPLIT>
__global__ __launch_bounds__(256) void k_gemm64(const __bf16* __restrict__ A, const __bf16* __restrict__ A2,
                                                const __bf16* __restrict__ Bt,
                                                const float* __restrict__ bias, __bf16* __restrict__ outb,
                                                float* __restrict__ outf, int M, int N, int K) {
  constexpr int BM = 64, BN = 64, BK = 64;
  __shared__ __bf16 As[2][BM * BK];
  __shared__ __bf16 Bs[2][BN * BK];
  const int tid = threadIdx.x;
  const int lane = tid & 63;
  const int wave = tid >> 6;
  const int wm = wave >> 1, wn = wave & 1;   // wave tile 32x32
  const size_t m0 = (size_t)blockIdx.x * BM;
  const size_t n0 = (size_t)blockIdx.y * BN;
  const int r0 = tid >> 3, g0 = tid & 7;
  const int gs0 = (g0 ^ (r0 & 7)) << 3;
  const int Astride = SPLIT ? 256 : K;

  f32x4 acc[2][2] = {};
  const int NT = K >> 6;

  {  // prologue: tile 0 (always from A)
    uint4 a0 = *(const uint4*)(A + (m0 + r0) * Astride + g0 * 8);
    uint4 a1 = *(const uint4*)(A + (m0 + r0 + 32) * Astride + g0 * 8);
    uint4 b0 = *(const uint4*)(Bt + (n0 + r0) * K + g0 * 8);
    uint4 b1 = *(const uint4*)(Bt + (n0 + r0 + 32) * K + g0 * 8);
    *(uint4*)&As[0][r0 * BK + gs0] = a0;
    *(uint4*)&As[0][(r0 + 32) * BK + gs0] = a1;
    *(uint4*)&Bs[0][r0 * BK + gs0] = b0;
    *(uint4*)&Bs[0][(r0 + 32) * BK + gs0] = b1;
  }
  __syncthreads();

  int buf = 0;
  for (int t = 0; t < NT; ++t) {
    const bool has = (t + 1 < NT);
    uint4 a0, a1, b0, b1;
    if (has) {
      int kt = (t + 1) << 6;
      const __bf16* Ab;
      int ko;
      if (SPLIT) { Ab = (kt < 256) ? A : A2; ko = kt & 255; }
      else       { Ab = A; ko = kt; }
      a0 = *(const uint4*)(Ab + (m0 + r0) * Astride + ko + g0 * 8);
      a1 = *(const uint4*)(Ab + (m0 + r0 + 32) * Astride + ko + g0 * 8);
      b0 = *(const uint4*)(Bt + (n0 + r0) * K + kt + g0 * 8);
      b1 = *(const uint4*)(Bt + (n0 + r0 + 32) * K + kt + g0 * 8);
    }
#pragma unroll
    for (int ks = 0; ks < BK; ks += 32) {
      const int kg = (ks >> 3) + (lane >> 4);
      bf16x8 af[2], bfv[2];
#pragma unroll
      for (int fm = 0; fm < 2; fm++) {
        int r = wm * 32 + fm * 16 + (lane & 15);
        af[fm] = *(const bf16x8*)&As[buf][r * BK + ((kg ^ (r & 7)) << 3)];
      }
#pragma unroll
      for (int fn = 0; fn < 2; fn++) {
        int r = wn * 32 + fn * 16 + (lane & 15);
        bfv[fn] = *(const bf16x8*)&Bs[buf][r * BK + ((kg ^ (r & 7)) << 3)];
      }
#pragma unroll
      for (int fm = 0; fm < 2; fm++)
#pragma unroll
        for (int fn = 0; fn < 2; fn++)
          acc[fm][fn] = __builtin_amdgcn_mfma_f32_16x16x32_bf16(af[fm], bfv[fn], acc[fm][fn], 0, 0, 0);
    }
    if (has) {
      *(uint4*)&As[buf ^ 1][r0 * BK + gs0] = a0;
      *(uint4*)&As[buf ^ 1][(r0 + 32) * BK + gs0] = a1;
      *(uint4*)&Bs[buf ^ 1][r0 * BK + gs0] = b0;
      *(uint4*)&Bs[buf ^ 1][(r0 + 32) * BK + gs0] = b1;
    }
    __syncthreads();
    buf ^= 1;
  }

#pragma unroll
  for (int fm = 0; fm < 2; fm++) {
#pragma unroll
    for (int fn = 0; fn < 2; fn++) {
      const size_t col = n0 + wn * 32 + fn * 16 + (lane & 15);
      float bv = (EPI == 4) ? 0.f : bias[col];
#pragma unroll
      for (int j = 0; j < 4; j++) {
        size_t row = m0 + wm * 32 + fm * 16 + ((lane >> 4) << 2) + j;
        size_t idx = row * (size_t)N + col;
        float v = acc[fm][fn][j] + bv;
        if (EPI == 1) {
          outb[idx] = (__bf16)silu_f(v);
        } else if (EPI == 2) {
          float nh = outf[idx] + v;
          outf[idx] = nh;
          outb[idx] = (__bf16)nh;
        } else {
          outb[idx] = (__bf16)v;
        }
      }
    }
  }
}

// ---------------- host ----------------
extern "C" void kernel_launch(void* const* d_in, const int* in_sizes, int n_in,
                              void* d_out, int out_size, void* d_ws, size_t ws_size,
                              hipStream_t stream) {
  const float* h_in    = (const float*)d_in[0];
  const float* x_in    = (const float*)d_in[1];
  const int*   ei      = (const int*)d_in[2];
  const float* emb_w   = (const float*)d_in[3];
  const float* emb_b   = (const float*)d_in[4];
  const float* out_w   = (const float*)d_in[5];
  const float* out_b   = (const float*)d_in[6];
  const float* edge_w1 = (const float*)d_in[7];
  const float* edge_b1 = (const float*)d_in[8];
  const float* edge_w2 = (const float*)d_in[9];
  const float* edge_b2 = (const float*)d_in[10];
  const float* node_w1 = (const float*)d_in[11];
  const float* node_b1 = (const float*)d_in[12];
  const float* node_w2 = (const float*)d_in[13];
  const float* node_b2 = (const float*)d_in[14];
  const float* coord_w1 = (const float*)d_in[15];
  const float* coord_b1 = (const float*)d_in[16];
  const float* coord_w2 = (const float*)d_in[17];
  const float* coord_b2 = (const float*)d_in[18];
  const float* coord_w3 = (const float*)d_in[19];

  char* p = (char*)d_ws;
  auto alloc = [&](size_t bytes) -> void* {
    void* r = (void*)p;
    p += (bytes + 255) & ~(size_t)255;
    return r;
  };
  __bf16* e1T  = (__bf16*)alloc((size_t)6 * 512 * 256 * 2);
  __bf16* e2T  = (__bf16*)alloc((size_t)6 * 256 * 256 * 2);
  __bf16* n1T  = (__bf16*)alloc((size_t)6 * 256 * 512 * 2);
  __bf16* n2T  = (__bf16*)alloc((size_t)6 * 256 * 256 * 2);
  __bf16* c1T  = (__bf16*)alloc((size_t)3 * 512 * 256 * 2);
  __bf16* c2T  = (__bf16*)alloc((size_t)3 * 256 * 256 * 2);
  __bf16* h16  = (__bf16*)alloc((size_t)NN * HD * 2);
  __bf16* PQ16 = (__bf16*)alloc((size_t)NN * 512 * 2);
  __bf16* m2p  = (__bf16*)alloc((size_t)NE * HD * 2);
  __bf16* agg16 = (__bf16*)alloc((size_t)NN * HD * 2);
  __bf16* u    = (__bf16*)alloc((size_t)NN * HD * 2);
  float* hf    = (float*)alloc((size_t)NN * HD * 4);
  float* xc    = (float*)alloc((size_t)NN * 3 * 4);
  float* d0p   = (float*)alloc((size_t)NE * 4);
  float* radp  = (float*)alloc((size_t)NE * 4);
  float* cdp   = (float*)alloc((size_t)NE * 3 * 4);
  float* transp = (float*)alloc((size_t)NE * 3 * 4);
  int* cnt     = (int*)alloc((size_t)NN * 4);
  int* offs    = (int*)alloc((size_t)(NN + 1) * 4);
  int* cursor  = (int*)alloc((size_t)NN * 4);
  int* elist   = (int*)alloc((size_t)NE * 4);
  int* rowp    = (int*)alloc((size_t)NE * 4);
  int* colp    = (int*)alloc((size_t)NE * 4);

  TJobs jobs;
  int nj = 0;
  for (int gi = 0; gi < 6; gi++) {
    jobs.j[nj++] = { edge_w1 + (size_t)gi * 514 * 256,             e1T + (size_t)gi * 512 * 256,             256, 256 };
    jobs.j[nj++] = { edge_w1 + (size_t)gi * 514 * 256 + 256 * 256, e1T + (size_t)gi * 512 * 256 + 256 * 256, 256, 256 };
    jobs.j[nj++] = { edge_w2 + (size_t)gi * 256 * 256,             e2T + (size_t)gi * 256 * 256,             256, 256 };
    jobs.j[nj++] = { node_w1 + (size_t)gi * 512 * 256,             n1T + (size_t)gi * 256 * 512,             512, 256 };
    jobs.j[nj++] = { node_w2 + (size_t)gi * 256 * 256,             n2T + (size_t)gi * 256 * 256,             256, 256 };
  }
  for (int b = 0; b < 3; b++) {
    jobs.j[nj++] = { coord_w1 + (size_t)b * 514 * 256,             c1T + (size_t)b * 512 * 256,              256, 256 };
    jobs.j[nj++] = { coord_w1 + (size_t)b * 514 * 256 + 256 * 256, c1T + (size_t)b * 512 * 256 + 256 * 256,  256, 256 };
    jobs.j[nj++] = { coord_w2 + (size_t)b * 256 * 256,             c2T + (size_t)b * 256 * 256,              256, 256 };
  }

  hipMemsetAsync(cnt, 0, (size_t)NN * 4, stream);
  k_transpose<<<dim3(16, 8, 39), 256, 0, stream>>>(jobs);
  k_hist<<<NE / 256, 256, 0, stream>>>(ei, cnt);
  k_scan<<<1, 1024, 0, stream>>>(cnt, offs, cursor);
  k_scatter<<<NE / 256, 256, 0, stream>>>(ei, cursor, elist);
  k_csrinit<<<NE / 256, 256, 0, stream>>>(elist, ei, x_in, rowp, colp, d0p, xc);
  k_embed<<<NN, 256, 0, stream>>>(h_in, emb_w, emb_b, hf, h16);

  int gi = 0;
  for (int b = 0; b < 3; b++) {
    k_geo<<<NE / 256, 256, 0, stream>>>(rowp, colp, xc, radp, cdp);
    for (int s = 0; s < 2; s++, gi++) {
      const float* w1 = edge_w1 + (size_t)gi * 514 * 256;
      k_gemm64<4, 0><<<dim3(64, 8), 256, 0, stream>>>(
          h16, nullptr, e1T + (size_t)gi * 512 * 256, nullptr, PQ16, nullptr, NN, 512, 256);
      k_edgeblk<0><<<NE / 128, 256, 0, stream>>>(
          PQ16, rowp, colp, radp, d0p, w1 + 512 * 256, w1 + 513 * 256, edge_b1 + gi * 256,
          e2T + (size_t)gi * 256 * 256, edge_b2 + gi * 256, m2p, nullptr, nullptr, nullptr);
      k_segsum<<<NN, 256, 0, stream>>>(m2p, offs, agg16);
      k_gemm64<1, 1><<<dim3(64, 4), 256, 0, stream>>>(
          h16, agg16, n1T + (size_t)gi * 256 * 512, node_b1 + gi * 256, u, nullptr, NN, 256, 512);
      k_gemm64<2, 0><<<dim3(64, 4), 256, 0, stream>>>(
          u, nullptr, n2T + (size_t)gi * 256 * 256, node_b2 + gi * 256, h16, hf, NN, 256, 256);
    }
    const float* w1c = coord_w1 + (size_t)b * 514 * 256;
    k_gemm64<4, 0><<<dim3(64, 8), 256, 0, stream>>>(
        h16, nullptr, c1T + (size_t)b * 512 * 256, nullptr, PQ16, nullptr, NN, 512, 256);
    k_edgeblk<1><<<NE / 128, 256, 0, stream>>>(
        PQ16, rowp, colp, radp, d0p, w1c + 512 * 256, w1c + 513 * 256, coord_b1 + b * 256,
        c2T + (size_t)b * 256 * 256, coord_b2 + b * 256, nullptr,
        coord_w3 + (size_t)b * 256, cdp, transp);
    k_xupd<<<NN / 256, 256, 0, stream>>>(transp, offs, xc);
  }
  k_out<<<256 + 48, 256, 0, stream>>>(hf, out_w, out_b, xc, (float*)d_out);
}

// Round 7
// 480.745 us; speedup vs baseline: 1.6634x; 1.6634x over previous
//
#include <hip/hip_runtime.h>
#include <hip/hip_bf16.h>
#include <cstdint>
#include <cstddef>

#define NN 4096
#define NE 65536
#define HD 256

typedef __attribute__((ext_vector_type(4))) float f32x4;
typedef __attribute__((ext_vector_type(8))) __bf16 bf16x8;

// fast silu: v * rcp(1 + exp2(-log2e * v)); rcp/exp are HW-approx (~1ulp), fine for bf16 out
static __device__ __forceinline__ float silu_f(float v) {
  float e = __builtin_amdgcn_exp2f(v * -1.442695040888963f);
  return v * __builtin_amdgcn_rcpf(1.f + e);
}

// ---------------- weight transpose/convert: f32 [K,N] -> bf16 [N,K] ----------
struct TJob { const float* src; __bf16* dst; int K; int N; };
struct TJobs { TJob j[39]; };

__global__ __launch_bounds__(256) void k_transpose(TJobs jobs) {
  TJob jb = jobs.j[blockIdx.z];
  int k0 = blockIdx.x << 5, n0 = blockIdx.y << 5;
  if (k0 >= jb.K || n0 >= jb.N) return;
  __shared__ float t[32][33];
  int tx = threadIdx.x & 31, ty = threadIdx.x >> 5;
#pragma unroll
  for (int r = ty; r < 32; r += 8)
    t[r][tx] = jb.src[(size_t)(k0 + r) * jb.N + n0 + tx];
  __syncthreads();
#pragma unroll
  for (int r = ty; r < 32; r += 8)
    jb.dst[(size_t)(n0 + r) * jb.K + k0 + tx] = (__bf16)t[tx][r];
}

// ---------------- CSR build ----------------
__global__ __launch_bounds__(256) void k_hist(const int* __restrict__ ei, int* __restrict__ cnt) {
  int e = blockIdx.x * 256 + threadIdx.x;
  atomicAdd(&cnt[ei[e]], 1);
}

__global__ __launch_bounds__(1024) void k_scan(const int* __restrict__ cnt, int* __restrict__ offs,
                                               int* __restrict__ cursor) {
  __shared__ int tmp[1024];
  int tid = threadIdx.x;
  int v[4]; int s = 0;
#pragma unroll
  for (int i = 0; i < 4; i++) { v[i] = cnt[tid * 4 + i]; s += v[i]; }
  tmp[tid] = s;
  __syncthreads();
  for (int o = 1; o < 1024; o <<= 1) {
    int t = (tid >= o) ? tmp[tid - o] : 0;
    __syncthreads();
    tmp[tid] += t;
    __syncthreads();
  }
  int base = (tid > 0) ? tmp[tid - 1] : 0;
#pragma unroll
  for (int i = 0; i < 4; i++) {
    offs[tid * 4 + i] = base; cursor[tid * 4 + i] = base; base += v[i];
  }
  if (tid == 1023) offs[4096] = base;
}

__global__ __launch_bounds__(256) void k_scatter(const int* __restrict__ ei, int* __restrict__ cursor,
                                                 int* __restrict__ elist) {
  int e = blockIdx.x * 256 + threadIdx.x;
  int pos = atomicAdd(&cursor[ei[e]], 1);
  elist[pos] = e;
}

// CSR metadata + dist0 (from initial x) + xc init
__global__ __launch_bounds__(256) void k_csrinit(const int* __restrict__ elist, const int* __restrict__ ei,
                                                 const float* __restrict__ x, int* __restrict__ rowp,
                                                 int* __restrict__ colp, float* __restrict__ d0p,
                                                 float* __restrict__ xc) {
  int i = blockIdx.x * 256 + threadIdx.x;
  if (i < NN * 3) xc[i] = x[i];
  int e = elist[i];
  int r = ei[e], c = ei[NE + e];
  rowp[i] = r; colp[i] = c;
  float dx = x[r * 3 + 0] - x[c * 3 + 0];
  float dy = x[r * 3 + 1] - x[c * 3 + 1];
  float dz = x[r * 3 + 2] - x[c * 3 + 2];
  d0p[i] = dx * dx + dy * dy + dz * dz;
}

// per-block geometry (radial + coord_diff) in CSR order, from current coords
__global__ __launch_bounds__(256) void k_geo(const int* __restrict__ rowp, const int* __restrict__ colp,
                                             const float* __restrict__ x, float* __restrict__ radp,
                                             float* __restrict__ cdp) {
  int i = blockIdx.x * 256 + threadIdx.x;
  int r = rowp[i], c = colp[i];
  float dx = x[r * 3 + 0] - x[c * 3 + 0];
  float dy = x[r * 3 + 1] - x[c * 3 + 1];
  float dz = x[r * 3 + 2] - x[c * 3 + 2];
  float rad = dx * dx + dy * dy + dz * dz;
  radp[i] = rad;
  float inv = 1.f / (sqrtf(rad + 1e-8f) + 1.f);
  cdp[i * 3 + 0] = dx * inv; cdp[i * 3 + 1] = dy * inv; cdp[i * 3 + 2] = dz * inv;
}

__global__ __launch_bounds__(256) void k_embed(const float* __restrict__ h0, const float* __restrict__ W,
                                               const float* __restrict__ b, float* __restrict__ hf,
                                               __bf16* __restrict__ h16) {
  int n = blockIdx.x, c = threadIdx.x;
  float s = b[c];
#pragma unroll
  for (int i = 0; i < 16; i++) s += h0[n * 16 + i] * W[i * 256 + c];
  hf[(size_t)n * HD + c] = s;
  h16[(size_t)n * HD + c] = (__bf16)s;
}

// bias512 tables: [9][512] = [b1 | zeros] for 6 edge GCLs then 3 coord blocks
__global__ __launch_bounds__(256) void k_mkbias(const float* __restrict__ eb1, const float* __restrict__ cb1,
                                                float* __restrict__ bias512) {
  int i = blockIdx.x * 256 + threadIdx.x;   // 18 blocks -> 9*512
  int g = i >> 9, r = i & 511;
  float v = 0.f;
  if (r < 256) v = (g < 6) ? eb1[g * 256 + r] : cb1[(g - 6) * 256 + r];
  bias512[i] = v;
}

// seg-sum over CSR (m2p CSR-ordered) -> agg16 = bf16(sum/100)
__global__ __launch_bounds__(256) void k_segsum(const __bf16* __restrict__ m2p, const int* __restrict__ offs,
                                                __bf16* __restrict__ agg16) {
  __shared__ float sd[8][256];
  int n = blockIdx.x, t = threadIdx.x;
  int g = t >> 5, l = t & 31;
  int c0 = l << 3;
  float a[8] = {};
  int ib = offs[n], ie = offs[n + 1];
  for (int i = ib + g; i < ie; i += 8) {
    bf16x8 v = *(const bf16x8*)(m2p + (size_t)i * 256 + c0);
#pragma unroll
    for (int j = 0; j < 8; j++) a[j] += (float)v[j];
  }
#pragma unroll
  for (int j = 0; j < 8; j++) sd[g][c0 + j] = a[j];
  __syncthreads();
  float s = 0.f;
#pragma unroll
  for (int j = 0; j < 8; j++) s += sd[j][t];
  agg16[(size_t)n * 256 + t] = (__bf16)(s * 0.01f);
}

__global__ __launch_bounds__(256) void k_xupd(const float* __restrict__ transp, const int* __restrict__ offs,
                                              float* __restrict__ xc) {
  int n = blockIdx.x * 256 + threadIdx.x;
  if (n >= NN) return;
  float a0 = 0.f, a1 = 0.f, a2 = 0.f;
  int i1 = offs[n + 1];
  for (int i = offs[n]; i < i1; i++) {
    a0 += transp[i * 3 + 0]; a1 += transp[i * 3 + 1]; a2 += transp[i * 3 + 2];
  }
  xc[n * 3 + 0] += a0 * 0.01f;
  xc[n * 3 + 1] += a1 * 0.01f;
  xc[n * 3 + 2] += a2 * 0.01f;
}

// final: out_h = hf@out_w + out_b ; out_x = xc
__global__ __launch_bounds__(256) void k_out(const float* __restrict__ hf, const float* __restrict__ W,
                                             const float* __restrict__ b, const float* __restrict__ xc,
                                             float* __restrict__ out) {
  int t = blockIdx.x * 256 + threadIdx.x;
  if (blockIdx.x < 256) {
    int n = t >> 4, j = t & 15;
    float s = b[j];
    for (int c = 0; c < 256; c++) s += hf[(size_t)n * HD + c] * W[c * 16 + j];
    out[n * 16 + j] = s;
  } else {
    int i = t - NN * 16;
    if (i < NN * 3) out[NN * 16 + i] = xc[i];
  }
}

// ---------------- fused edge-block kernel (v4.1: register-A, fast silu, b1 pre-folded) ----------------
// Block = 4 waves = 64 CSR-ordered edges; each wave owns 16 edges.
// A-fragment per-lane in regs: gather PQ[row]/PQ[col] 16B + silu (b1 already folded into PQ's P half).
// B = W2^T staged [2][256][32] in LDS, reg-prefetched, 1 barrier/K-step.
// EPI 0: m2p[i][col] = silu(out + b2)  (LDS-restaged coalesced stores)
// EPI 1: trans[i] = cdp[i] * sum_col(silu(out+b2)*w3[col])
template <int EPI>
__global__ __launch_bounds__(256, 4) void k_edgeblk(
    const __bf16* __restrict__ PQ, const int* __restrict__ rowp, const int* __restrict__ colp,
    const float* __restrict__ radp, const float* __restrict__ d0p,
    const float* __restrict__ w1r, const float* __restrict__ w1d,
    const __bf16* __restrict__ Bt, const float* __restrict__ b2,
    __bf16* __restrict__ m2p,
    const float* __restrict__ w3, const float* __restrict__ cdp, float* __restrict__ transp) {
  __shared__ alignas(16) char smem[36864];
  float*  wgt = (float*)smem;                    // [4][256]: w1r,w1d,b2,w3  (4 KB)
  __bf16* Bs0 = (__bf16*)(smem + 4096);          // [256][32] buffer 0 (16 KB)
  __bf16* Bs1 = (__bf16*)(smem + 4096 + 16384);  // buffer 1
  float*  reds = (float*)(smem + 4096);          // EPI1 overlay (64 floats)

  const int tid = threadIdx.x;
  const int lane = tid & 63;
  const int w = tid >> 6;            // wave 0..3
  const int l15 = lane & 15;
  const int kg = lane >> 4;          // k-granule 0..3
  const int R0 = blockIdx.x * 64;
  const int rowg = R0 + w * 16 + l15;

  const __bf16* pBase = PQ + (size_t)rowp[rowg] * 512;
  const __bf16* qBase = PQ + (size_t)colp[rowg] * 512 + 256;
  const float rad = radp[rowg], dd0 = d0p[rowg];

  // stage weights into LDS
  wgt[tid]       = w1r[tid];
  wgt[256 + tid] = w1d[tid];
  wgt[512 + tid] = b2[tid];
  if (EPI == 1) wgt[768 + tid] = w3[tid];

  // B slot mapping: slot s = q*256+tid; phys (n = s>>2, g = s&3) holds logical granule g^swz(n)
  int srcOff[4], ldsOff[4];
#pragma unroll
  for (int q = 0; q < 4; q++) {
    int s = q * 256 + tid;
    int n = s >> 2, g = s & 3;
    srcOff[q] = n * 256 + ((g ^ ((n >> 1) & 3)) << 3);
    ldsOff[q] = s * 8;
  }

  // prologue: tile 0 to Bs0, A-gather for step 0
  uint4 rb[4];
#pragma unroll
  for (int q = 0; q < 4; q++) rb[q] = *(const uint4*)(Bt + srcOff[q]);
  bf16x8 pvc = *(const bf16x8*)(pBase + kg * 8);
  bf16x8 qvc = *(const bf16x8*)(qBase + kg * 8);
#pragma unroll
  for (int q = 0; q < 4; q++) *(uint4*)&Bs0[ldsOff[q]] = rb[q];
  __syncthreads();

  f32x4 acc[16] = {};

#pragma unroll
  for (int t = 0; t < 8; t++) {
    const __bf16* Bcur = (t & 1) ? Bs1 : Bs0;
    __bf16*       Bnxt = (t & 1) ? Bs0 : Bs1;
    bf16x8 pvn, qvn;
    if (t < 7) {  // issue next-tile loads early (latency hides under silu+MFMA)
      int kt = (t + 1) * 32;
#pragma unroll
      for (int q = 0; q < 4; q++) rb[q] = *(const uint4*)(Bt + kt + srcOff[q]);
      pvn = *(const bf16x8*)(pBase + kt + kg * 8);
      qvn = *(const bf16x8*)(qBase + kt + kg * 8);
    }
    // silu -> A fragment (row = l15's edge, k = t*32 + kg*8 + j)
    const int k0 = t * 32 + kg * 8;
    f32x4 wr0 = *(const f32x4*)&wgt[k0],       wr1 = *(const f32x4*)&wgt[k0 + 4];
    f32x4 wd0 = *(const f32x4*)&wgt[256 + k0], wd1 = *(const f32x4*)&wgt[256 + k0 + 4];
    bf16x8 af;
#pragma unroll
    for (int j = 0; j < 4; j++)
      af[j] = (__bf16)silu_f((float)pvc[j] + (float)qvc[j] + rad * wr0[j] + dd0 * wd0[j]);
#pragma unroll
    for (int j = 0; j < 4; j++)
      af[4 + j] = (__bf16)silu_f((float)pvc[4 + j] + (float)qvc[4 + j] + rad * wr1[j] + dd0 * wd1[j]);
    // 16 MFMAs: all 256 output cols
#pragma unroll
    for (int fn = 0; fn < 16; fn++) {
      int n = fn * 16 + l15;
      bf16x8 bf = *(const bf16x8*)&Bcur[n * 32 + ((kg ^ ((n >> 1) & 3)) << 3)];
      acc[fn] = __builtin_amdgcn_mfma_f32_16x16x32_bf16(af, bf, acc[fn], 0, 0, 0);
    }
    if (t < 7) {
#pragma unroll
      for (int q = 0; q < 4; q++) *(uint4*)&Bnxt[ldsOff[q]] = rb[q];
      pvc = pvn; qvc = qvn;
    }
    __syncthreads();
  }

  // ---- epilogue ----
  if (EPI == 0) {
    // per-wave LDS restage (2 passes x 8 rows) -> coalesced 16B row stores
    __bf16* ep = (__bf16*)(smem + 4096 + w * 4224);  // [8][264]
#pragma unroll
    for (int p = 0; p < 2; p++) {
      if ((kg >> 1) == p) {
        int rl = (kg & 1) * 4;
#pragma unroll
        for (int fn = 0; fn < 16; fn++) {
          int col = fn * 16 + l15;
          float bv = wgt[512 + col];
#pragma unroll
          for (int j = 0; j < 4; j++)
            ep[(rl + j) * 264 + col] = (__bf16)silu_f(acc[fn][j] + bv);
        }
      }
      __syncthreads();
#pragma unroll
      for (int i = 0; i < 4; i++) {
        int r = i * 2 + (lane >> 5);
        int g = lane & 31;
        uint4 v = *(const uint4*)&ep[r * 264 + g * 8];
        *(uint4*)(m2p + ((size_t)(R0 + w * 16 + p * 8 + r)) * 256 + g * 8) = v;
      }
      __syncthreads();
    }
  } else {
    float s[4] = {0.f, 0.f, 0.f, 0.f};
#pragma unroll
    for (int fn = 0; fn < 16; fn++) {
      int col = fn * 16 + l15;
      float bv = wgt[512 + col], wv = wgt[768 + col];
#pragma unroll
      for (int j = 0; j < 4; j++)
        s[j] += silu_f(acc[fn][j] + bv) * wv;
    }
#pragma unroll
    for (int off = 1; off < 16; off <<= 1)
#pragma unroll
      for (int j = 0; j < 4; j++)
        s[j] += __shfl_xor(s[j], off, 64);
    __syncthreads();
    if (l15 == 0) {
#pragma unroll
      for (int j = 0; j < 4; j++)
        reds[w * 16 + kg * 4 + j] = s[j];
    }
    __syncthreads();
    if (tid < 64) {
      float sv = reds[tid];
      size_t i = (size_t)R0 + tid;
      transp[i * 3 + 0] = cdp[i * 3 + 0] * sv;
      transp[i * 3 + 1] = cdp[i * 3 + 1] * sv;
      transp[i * 3 + 2] = cdp[i * 3 + 2] * sv;
    }
  }
}

// ---------------- 64x64 MFMA GEMM, 2-phase double-buffered ----------------
// C = epi(A[M,K] @ Bt[N,K]^T + bias).
// SPLIT=1: logical K=512, A-rows = [A(256) || A2(256)], both row-stride 256.
// EPI: 1 silu->bf16, 2 residual f32+=v & bf16 out, 4 plain bf16 (no bias), 5 bias+bf16
template <int EPI, int SPLIT>
__global__ __launch_bounds__(256) void k_gemm64(const __bf16* __restrict__ A, const __bf16* __restrict__ A2,
                                                const __bf16* __restrict__ Bt,
                                                const float* __restrict__ bias, __bf16* __restrict__ outb,
                                                float* __restrict__ outf, int M, int N, int K) {
  constexpr int BM = 64, BN = 64, BK = 64;
  __shared__ __bf16 As[2][BM * BK];
  __shared__ __bf16 Bs[2][BN * BK];
  const int tid = threadIdx.x;
  const int lane = tid & 63;
  const int wave = tid >> 6;
  const int wm = wave >> 1, wn = wave & 1;   // wave tile 32x32
  const size_t m0 = (size_t)blockIdx.x * BM;
  const size_t n0 = (size_t)blockIdx.y * BN;
  const int r0 = tid >> 3, g0 = tid & 7;
  const int gs0 = (g0 ^ (r0 & 7)) << 3;
  const int Astride = SPLIT ? 256 : K;

  f32x4 acc[2][2] = {};
  const int NT = K >> 6;

  {  // prologue: tile 0 (always from A)
    uint4 a0 = *(const uint4*)(A + (m0 + r0) * Astride + g0 * 8);
    uint4 a1 = *(const uint4*)(A + (m0 + r0 + 32) * Astride + g0 * 8);
    uint4 b0 = *(const uint4*)(Bt + (n0 + r0) * K + g0 * 8);
    uint4 b1 = *(const uint4*)(Bt + (n0 + r0 + 32) * K + g0 * 8);
    *(uint4*)&As[0][r0 * BK + gs0] = a0;
    *(uint4*)&As[0][(r0 + 32) * BK + gs0] = a1;
    *(uint4*)&Bs[0][r0 * BK + gs0] = b0;
    *(uint4*)&Bs[0][(r0 + 32) * BK + gs0] = b1;
  }
  __syncthreads();

  int buf = 0;
  for (int t = 0; t < NT; ++t) {
    const bool has = (t + 1 < NT);
    uint4 a0, a1, b0, b1;
    if (has) {
      int kt = (t + 1) << 6;
      const __bf16* Ab;
      int ko;
      if (SPLIT) { Ab = (kt < 256) ? A : A2; ko = kt & 255; }
      else       { Ab = A; ko = kt; }
      a0 = *(const uint4*)(Ab + (m0 + r0) * Astride + ko + g0 * 8);
      a1 = *(const uint4*)(Ab + (m0 + r0 + 32) * Astride + ko + g0 * 8);
      b0 = *(const uint4*)(Bt + (n0 + r0) * K + kt + g0 * 8);
      b1 = *(const uint4*)(Bt + (n0 + r0 + 32) * K + kt + g0 * 8);
    }
#pragma unroll
    for (int ks = 0; ks < BK; ks += 32) {
      const int kg = (ks >> 3) + (lane >> 4);
      bf16x8 af[2], bfv[2];
#pragma unroll
      for (int fm = 0; fm < 2; fm++) {
        int r = wm * 32 + fm * 16 + (lane & 15);
        af[fm] = *(const bf16x8*)&As[buf][r * BK + ((kg ^ (r & 7)) << 3)];
      }
#pragma unroll
      for (int fn = 0; fn < 2; fn++) {
        int r = wn * 32 + fn * 16 + (lane & 15);
        bfv[fn] = *(const bf16x8*)&Bs[buf][r * BK + ((kg ^ (r & 7)) << 3)];
      }
#pragma unroll
      for (int fm = 0; fm < 2; fm++)
#pragma unroll
        for (int fn = 0; fn < 2; fn++)
          acc[fm][fn] = __builtin_amdgcn_mfma_f32_16x16x32_bf16(af[fm], bfv[fn], acc[fm][fn], 0, 0, 0);
    }
    if (has) {
      *(uint4*)&As[buf ^ 1][r0 * BK + gs0] = a0;
      *(uint4*)&As[buf ^ 1][(r0 + 32) * BK + gs0] = a1;
      *(uint4*)&Bs[buf ^ 1][r0 * BK + gs0] = b0;
      *(uint4*)&Bs[buf ^ 1][(r0 + 32) * BK + gs0] = b1;
    }
    __syncthreads();
    buf ^= 1;
  }

#pragma unroll
  for (int fm = 0; fm < 2; fm++) {
#pragma unroll
    for (int fn = 0; fn < 2; fn++) {
      const size_t col = n0 + wn * 32 + fn * 16 + (lane & 15);
      float bv = (EPI == 4) ? 0.f : bias[col];
#pragma unroll
      for (int j = 0; j < 4; j++) {
        size_t row = m0 + wm * 32 + fm * 16 + ((lane >> 4) << 2) + j;
        size_t idx = row * (size_t)N + col;
        float v = acc[fm][fn][j] + bv;
        if (EPI == 1) {
          outb[idx] = (__bf16)silu_f(v);
        } else if (EPI == 2) {
          float nh = outf[idx] + v;
          outf[idx] = nh;
          outb[idx] = (__bf16)nh;
        } else {
          outb[idx] = (__bf16)v;
        }
      }
    }
  }
}

// ---------------- host ----------------
extern "C" void kernel_launch(void* const* d_in, const int* in_sizes, int n_in,
                              void* d_out, int out_size, void* d_ws, size_t ws_size,
                              hipStream_t stream) {
  const float* h_in    = (const float*)d_in[0];
  const float* x_in    = (const float*)d_in[1];
  const int*   ei      = (const int*)d_in[2];
  const float* emb_w   = (const float*)d_in[3];
  const float* emb_b   = (const float*)d_in[4];
  const float* out_w   = (const float*)d_in[5];
  const float* out_b   = (const float*)d_in[6];
  const float* edge_w1 = (const float*)d_in[7];
  const float* edge_b1 = (const float*)d_in[8];
  const float* edge_w2 = (const float*)d_in[9];
  const float* edge_b2 = (const float*)d_in[10];
  const float* node_w1 = (const float*)d_in[11];
  const float* node_b1 = (const float*)d_in[12];
  const float* node_w2 = (const float*)d_in[13];
  const float* node_b2 = (const float*)d_in[14];
  const float* coord_w1 = (const float*)d_in[15];
  const float* coord_b1 = (const float*)d_in[16];
  const float* coord_w2 = (const float*)d_in[17];
  const float* coord_b2 = (const float*)d_in[18];
  const float* coord_w3 = (const float*)d_in[19];

  char* p = (char*)d_ws;
  auto alloc = [&](size_t bytes) -> void* {
    void* r = (void*)p;
    p += (bytes + 255) & ~(size_t)255;
    return r;
  };
  __bf16* e1T  = (__bf16*)alloc((size_t)6 * 512 * 256 * 2);
  __bf16* e2T  = (__bf16*)alloc((size_t)6 * 256 * 256 * 2);
  __bf16* n1T  = (__bf16*)alloc((size_t)6 * 256 * 512 * 2);
  __bf16* n2T  = (__bf16*)alloc((size_t)6 * 256 * 256 * 2);
  __bf16* c1T  = (__bf16*)alloc((size_t)3 * 512 * 256 * 2);
  __bf16* c2T  = (__bf16*)alloc((size_t)3 * 256 * 256 * 2);
  __bf16* h16  = (__bf16*)alloc((size_t)NN * HD * 2);
  __bf16* PQ16 = (__bf16*)alloc((size_t)NN * 512 * 2);
  __bf16* m2p  = (__bf16*)alloc((size_t)NE * HD * 2);
  __bf16* agg16 = (__bf16*)alloc((size_t)NN * HD * 2);
  __bf16* u    = (__bf16*)alloc((size_t)NN * HD * 2);
  float* hf    = (float*)alloc((size_t)NN * HD * 4);
  float* xc    = (float*)alloc((size_t)NN * 3 * 4);
  float* d0p   = (float*)alloc((size_t)NE * 4);
  float* radp  = (float*)alloc((size_t)NE * 4);
  float* cdp   = (float*)alloc((size_t)NE * 3 * 4);
  float* transp = (float*)alloc((size_t)NE * 3 * 4);
  float* bias512 = (float*)alloc((size_t)9 * 512 * 4);
  int* cnt     = (int*)alloc((size_t)NN * 4);
  int* offs    = (int*)alloc((size_t)(NN + 1) * 4);
  int* cursor  = (int*)alloc((size_t)NN * 4);
  int* elist   = (int*)alloc((size_t)NE * 4);
  int* rowp    = (int*)alloc((size_t)NE * 4);
  int* colp    = (int*)alloc((size_t)NE * 4);

  TJobs jobs;
  int nj = 0;
  for (int gi = 0; gi < 6; gi++) {
    jobs.j[nj++] = { edge_w1 + (size_t)gi * 514 * 256,             e1T + (size_t)gi * 512 * 256,             256, 256 };
    jobs.j[nj++] = { edge_w1 + (size_t)gi * 514 * 256 + 256 * 256, e1T + (size_t)gi * 512 * 256 + 256 * 256, 256, 256 };
    jobs.j[nj++] = { edge_w2 + (size_t)gi * 256 * 256,             e2T + (size_t)gi * 256 * 256,             256, 256 };
    jobs.j[nj++] = { node_w1 + (size_t)gi * 512 * 256,             n1T + (size_t)gi * 256 * 512,             512, 256 };
    jobs.j[nj++] = { node_w2 + (size_t)gi * 256 * 256,             n2T + (size_t)gi * 256 * 256,             256, 256 };
  }
  for (int b = 0; b < 3; b++) {
    jobs.j[nj++] = { coord_w1 + (size_t)b * 514 * 256,             c1T + (size_t)b * 512 * 256,              256, 256 };
    jobs.j[nj++] = { coord_w1 + (size_t)b * 514 * 256 + 256 * 256, c1T + (size_t)b * 512 * 256 + 256 * 256,  256, 256 };
    jobs.j[nj++] = { coord_w2 + (size_t)b * 256 * 256,             c2T + (size_t)b * 256 * 256,              256, 256 };
  }

  hipMemsetAsync(cnt, 0, (size_t)NN * 4, stream);
  k_transpose<<<dim3(16, 8, 39), 256, 0, stream>>>(jobs);
  k_hist<<<NE / 256, 256, 0, stream>>>(ei, cnt);
  k_scan<<<1, 1024, 0, stream>>>(cnt, offs, cursor);
  k_scatter<<<NE / 256, 256, 0, stream>>>(ei, cursor, elist);
  k_csrinit<<<NE / 256, 256, 0, stream>>>(elist, ei, x_in, rowp, colp, d0p, xc);
  k_mkbias<<<18, 256, 0, stream>>>(edge_b1, coord_b1, bias512);
  k_embed<<<NN, 256, 0, stream>>>(h_in, emb_w, emb_b, hf, h16);

  int gi = 0;
  for (int b = 0; b < 3; b++) {
    k_geo<<<NE / 256, 256, 0, stream>>>(rowp, colp, xc, radp, cdp);
    for (int s = 0; s < 2; s++, gi++) {
      const float* w1 = edge_w1 + (size_t)gi * 514 * 256;
      // PQ = h @ [W1a|W1b] + [b1|0]  -> bf16
      k_gemm64<5, 0><<<dim3(64, 8), 256, 0, stream>>>(
          h16, nullptr, e1T + (size_t)gi * 512 * 256, bias512 + gi * 512, PQ16, nullptr, NN, 512, 256);
      k_edgeblk<0><<<NE / 64, 256, 0, stream>>>(
          PQ16, rowp, colp, radp, d0p, w1 + 512 * 256, w1 + 513 * 256,
          e2T + (size_t)gi * 256 * 256, edge_b2 + gi * 256, m2p, nullptr, nullptr, nullptr);
      k_segsum<<<NN, 256, 0, stream>>>(m2p, offs, agg16);
      k_gemm64<1, 1><<<dim3(64, 4), 256, 0, stream>>>(
          h16, agg16, n1T + (size_t)gi * 256 * 512, node_b1 + gi * 256, u, nullptr, NN, 256, 512);
      k_gemm64<2, 0><<<dim3(64, 4), 256, 0, stream>>>(
          u, nullptr, n2T + (size_t)gi * 256 * 256, node_b2 + gi * 256, h16, hf, NN, 256, 256);
    }
    const float* w1c = coord_w1 + (size_t)b * 514 * 256;
    k_gemm64<5, 0><<<dim3(64, 8), 256, 0, stream>>>(
        h16, nullptr, c1T + (size_t)b * 512 * 256, bias512 + (6 + b) * 512, PQ16, nullptr, NN, 512, 256);
    k_edgeblk<1><<<NE / 64, 256, 0, stream>>>(
        PQ16, rowp, colp, radp, d0p, w1c + 512 * 256, w1c + 513 * 256,
        c2T + (size_t)b * 256 * 256, coord_b2 + b * 256, nullptr,
        coord_w3 + (size_t)b * 256, cdp, transp);
    k_xupd<<<NN / 256, 256, 0, stream>>>(transp, offs, xc);
  }
  k_out<<<256 + 48, 256, 0, stream>>>(hf, out_w, out_b, xc, (float*)d_out);
}

// Round 8
// 460.000 us; speedup vs baseline: 1.7384x; 1.0451x over previous
//
#include <hip/hip_runtime.h>
#include <hip/hip_bf16.h>
#include <cstdint>
#include <cstddef>

#define NN 4096
#define NE 65536
#define HD 256

typedef __attribute__((ext_vector_type(4))) float f32x4;
typedef __attribute__((ext_vector_type(8))) __bf16 bf16x8;

// fast silu: v * rcp(1 + exp2(-log2e * v))
static __device__ __forceinline__ float silu_f(float v) {
  float e = __builtin_amdgcn_exp2f(v * -1.442695040888963f);
  return v * __builtin_amdgcn_rcpf(1.f + e);
}

// ---------------- weight transpose/convert: f32 [K,N] -> bf16 [N,K] ----------
struct TJob { const float* src; __bf16* dst; int K; int N; };
struct TJobs { TJob j[39]; };

__global__ __launch_bounds__(256) void k_transpose(TJobs jobs) {
  TJob jb = jobs.j[blockIdx.z];
  int k0 = blockIdx.x << 5, n0 = blockIdx.y << 5;
  if (k0 >= jb.K || n0 >= jb.N) return;
  __shared__ float t[32][33];
  int tx = threadIdx.x & 31, ty = threadIdx.x >> 5;
#pragma unroll
  for (int r = ty; r < 32; r += 8)
    t[r][tx] = jb.src[(size_t)(k0 + r) * jb.N + n0 + tx];
  __syncthreads();
#pragma unroll
  for (int r = ty; r < 32; r += 8)
    jb.dst[(size_t)(n0 + r) * jb.K + k0 + tx] = (__bf16)t[tx][r];
}

// ---------------- CSR build ----------------
__global__ __launch_bounds__(256) void k_hist(const int* __restrict__ ei, int* __restrict__ cnt) {
  int e = blockIdx.x * 256 + threadIdx.x;
  atomicAdd(&cnt[ei[e]], 1);
}

__global__ __launch_bounds__(1024) void k_scan(const int* __restrict__ cnt, int* __restrict__ offs,
                                               int* __restrict__ cursor) {
  __shared__ int tmp[1024];
  int tid = threadIdx.x;
  int v[4]; int s = 0;
#pragma unroll
  for (int i = 0; i < 4; i++) { v[i] = cnt[tid * 4 + i]; s += v[i]; }
  tmp[tid] = s;
  __syncthreads();
  for (int o = 1; o < 1024; o <<= 1) {
    int t = (tid >= o) ? tmp[tid - o] : 0;
    __syncthreads();
    tmp[tid] += t;
    __syncthreads();
  }
  int base = (tid > 0) ? tmp[tid - 1] : 0;
#pragma unroll
  for (int i = 0; i < 4; i++) {
    offs[tid * 4 + i] = base; cursor[tid * 4 + i] = base; base += v[i];
  }
  if (tid == 1023) offs[4096] = base;
}

__global__ __launch_bounds__(256) void k_scatter(const int* __restrict__ ei, int* __restrict__ cursor,
                                                 int* __restrict__ elist) {
  int e = blockIdx.x * 256 + threadIdx.x;
  int pos = atomicAdd(&cursor[ei[e]], 1);
  elist[pos] = e;
}

// CSR metadata + dist0 (from initial x) + xc init
__global__ __launch_bounds__(256) void k_csrinit(const int* __restrict__ elist, const int* __restrict__ ei,
                                                 const float* __restrict__ x, int* __restrict__ rowp,
                                                 int* __restrict__ colp, float* __restrict__ d0p,
                                                 float* __restrict__ xc) {
  int i = blockIdx.x * 256 + threadIdx.x;
  if (i < NN * 3) xc[i] = x[i];
  int e = elist[i];
  int r = ei[e], c = ei[NE + e];
  rowp[i] = r; colp[i] = c;
  float dx = x[r * 3 + 0] - x[c * 3 + 0];
  float dy = x[r * 3 + 1] - x[c * 3 + 1];
  float dz = x[r * 3 + 2] - x[c * 3 + 2];
  d0p[i] = dx * dx + dy * dy + dz * dz;
}

// per-block geometry (radial + coord_diff) in CSR order, from current coords
__global__ __launch_bounds__(256) void k_geo(const int* __restrict__ rowp, const int* __restrict__ colp,
                                             const float* __restrict__ x, float* __restrict__ radp,
                                             float* __restrict__ cdp) {
  int i = blockIdx.x * 256 + threadIdx.x;
  int r = rowp[i], c = colp[i];
  float dx = x[r * 3 + 0] - x[c * 3 + 0];
  float dy = x[r * 3 + 1] - x[c * 3 + 1];
  float dz = x[r * 3 + 2] - x[c * 3 + 2];
  float rad = dx * dx + dy * dy + dz * dz;
  radp[i] = rad;
  float inv = 1.f / (sqrtf(rad + 1e-8f) + 1.f);
  cdp[i * 3 + 0] = dx * inv; cdp[i * 3 + 1] = dy * inv; cdp[i * 3 + 2] = dz * inv;
}

__global__ __launch_bounds__(256) void k_embed(const float* __restrict__ h0, const float* __restrict__ W,
                                               const float* __restrict__ b, float* __restrict__ hf,
                                               __bf16* __restrict__ h16) {
  int n = blockIdx.x, c = threadIdx.x;
  float s = b[c];
#pragma unroll
  for (int i = 0; i < 16; i++) s += h0[n * 16 + i] * W[i * 256 + c];
  hf[(size_t)n * HD + c] = s;
  h16[(size_t)n * HD + c] = (__bf16)s;
}

// bias512 tables: [9][512] = [b1 | zeros] for 6 edge GCLs then 3 coord blocks
__global__ __launch_bounds__(256) void k_mkbias(const float* __restrict__ eb1, const float* __restrict__ cb1,
                                                float* __restrict__ bias512) {
  int i = blockIdx.x * 256 + threadIdx.x;
  int g = i >> 9, r = i & 511;
  float v = 0.f;
  if (r < 256) v = (g < 6) ? eb1[g * 256 + r] : cb1[(g - 6) * 256 + r];
  bias512[i] = v;
}

// seg-sum over CSR (m2p CSR-ordered) -> agg16 = bf16(sum/100)
__global__ __launch_bounds__(256) void k_segsum(const __bf16* __restrict__ m2p, const int* __restrict__ offs,
                                                __bf16* __restrict__ agg16) {
  __shared__ float sd[8][256];
  int n = blockIdx.x, t = threadIdx.x;
  int g = t >> 5, l = t & 31;
  int c0 = l << 3;
  float a[8] = {};
  int ib = offs[n], ie = offs[n + 1];
  for (int i = ib + g; i < ie; i += 8) {
    bf16x8 v = *(const bf16x8*)(m2p + (size_t)i * 256 + c0);
#pragma unroll
    for (int j = 0; j < 8; j++) a[j] += (float)v[j];
  }
#pragma unroll
  for (int j = 0; j < 8; j++) sd[g][c0 + j] = a[j];
  __syncthreads();
  float s = 0.f;
#pragma unroll
  for (int j = 0; j < 8; j++) s += sd[j][t];
  agg16[(size_t)n * 256 + t] = (__bf16)(s * 0.01f);
}

__global__ __launch_bounds__(256) void k_xupd(const float* __restrict__ transp, const int* __restrict__ offs,
                                              float* __restrict__ xc) {
  int n = blockIdx.x * 256 + threadIdx.x;
  if (n >= NN) return;
  float a0 = 0.f, a1 = 0.f, a2 = 0.f;
  int i1 = offs[n + 1];
  for (int i = offs[n]; i < i1; i++) {
    a0 += transp[i * 3 + 0]; a1 += transp[i * 3 + 1]; a2 += transp[i * 3 + 2];
  }
  xc[n * 3 + 0] += a0 * 0.01f;
  xc[n * 3 + 1] += a1 * 0.01f;
  xc[n * 3 + 2] += a2 * 0.01f;
}

// final: out_h = hf@out_w + out_b ; out_x = xc
__global__ __launch_bounds__(256) void k_out(const float* __restrict__ hf, const float* __restrict__ W,
                                             const float* __restrict__ b, const float* __restrict__ xc,
                                             float* __restrict__ out) {
  int t = blockIdx.x * 256 + threadIdx.x;
  if (blockIdx.x < 256) {
    int n = t >> 4, j = t & 15;
    float s = b[j];
    for (int c = 0; c < 256; c++) s += hf[(size_t)n * HD + c] * W[c * 16 + j];
    out[n * 16 + j] = s;
  } else {
    int i = t - NN * 16;
    if (i < NN * 3) out[NN * 16 + i] = xc[i];
  }
}

// ---------------- fused edge-block kernel (v4.2: 8 waves, global_load_lds, setprio) -------
// Block = 8 waves = 128 CSR-ordered edges; each wave owns 16 edges, all 256 cols.
// A-fragment per-lane in regs: gather PQ[row]/PQ[col] 16B + silu (b1 pre-folded into PQ).
// B = W2^T staged [2][256][32] in LDS via global_load_lds (pre-swizzled global src,
// linear LDS dest), 1 barrier per K-step.
// EPI 0: m2p[i][col] = silu(out + b2)  (LDS-restaged coalesced stores)
// EPI 1: trans[i] = cdp[i] * sum_col(silu(out+b2)*w3[col])
template <int EPI>
__global__ __launch_bounds__(512, 4) void k_edgeblk(
    const __bf16* __restrict__ PQ, const int* __restrict__ rowp, const int* __restrict__ colp,
    const float* __restrict__ radp, const float* __restrict__ d0p,
    const float* __restrict__ w1r, const float* __restrict__ w1d,
    const __bf16* __restrict__ Bt, const float* __restrict__ b2,
    __bf16* __restrict__ m2p,
    const float* __restrict__ w3, const float* __restrict__ cdp, float* __restrict__ transp) {
  __shared__ alignas(16) char smem[37888];
  float*  wgt = (float*)smem;                    // [3..4][256]: w1r,w1d,b2,(w3)
  __bf16* Bs0 = (__bf16*)(smem + 4096);          // [256][32] buffer 0 (16 KB), slot-linear
  __bf16* Bs1 = (__bf16*)(smem + 4096 + 16384);  // buffer 1
  float*  reds = (float*)(smem + 4096);          // EPI1 overlay (128 floats)

  const int tid = threadIdx.x;
  const int lane = tid & 63;
  const int w = tid >> 6;            // wave 0..7
  const int l15 = lane & 15;
  const int kg = lane >> 4;          // k-granule 0..3
  const int R0 = blockIdx.x * 128;
  const int rowg = R0 + w * 16 + l15;

  const __bf16* pBase = PQ + (size_t)rowp[rowg] * 512;
  const __bf16* qBase = PQ + (size_t)colp[rowg] * 512 + 256;
  const float rad = radp[rowg], dd0 = d0p[rowg];

  // stage weights into LDS (split across the two thread halves)
  if (tid < 256) {
    wgt[tid]       = w1r[tid];
    wgt[256 + tid] = w1d[tid];
  } else {
    int t2 = tid - 256;
    wgt[512 + t2] = b2[t2];
    if (EPI == 1) wgt[768 + t2] = w3[t2];
  }

  // B staging: slot s = q*512 + tid holds row n=s>>2, phys granule g=s&3, whose data is
  // logical granule g^((n>>1)&3) -> pre-swizzled GLOBAL source + LINEAR LDS dest (DMA-able).
  int srcOff[2];
#pragma unroll
  for (int q = 0; q < 2; q++) {
    int s = q * 512 + tid;
    int n = s >> 2, g = s & 3;
    srcOff[q] = n * 256 + ((g ^ ((n >> 1) & 3)) << 3);
  }
  const int dstE0 = (0 * 512 + (w << 6)) * 8;   // elem offset of wave-uniform DMA base, q=0
  const int dstE1 = (1 * 512 + (w << 6)) * 8;   // q=1

  // prologue: DMA tile 0 into Bs0; A-gather for step 0
  __builtin_amdgcn_global_load_lds((const unsigned int*)(Bt + srcOff[0]),
                                   (unsigned int*)(Bs0 + dstE0), 16, 0, 0);
  __builtin_amdgcn_global_load_lds((const unsigned int*)(Bt + srcOff[1]),
                                   (unsigned int*)(Bs0 + dstE1), 16, 0, 0);
  bf16x8 pvc = *(const bf16x8*)(pBase + kg * 8);
  bf16x8 qvc = *(const bf16x8*)(qBase + kg * 8);
  __syncthreads();

  f32x4 acc[16] = {};

#pragma unroll
  for (int t = 0; t < 8; t++) {
    const __bf16* Bcur = (t & 1) ? Bs1 : Bs0;
    __bf16*       Bnxt = (t & 1) ? Bs0 : Bs1;
    bf16x8 pvn, qvn;
    if (t < 7) {   // DMA next B tile + issue PQ prefetch early; latency hides under silu+MFMA
      int kt = (t + 1) * 32;
      __builtin_amdgcn_global_load_lds((const unsigned int*)(Bt + kt + srcOff[0]),
                                       (unsigned int*)(Bnxt + dstE0), 16, 0, 0);
      __builtin_amdgcn_global_load_lds((const unsigned int*)(Bt + kt + srcOff[1]),
                                       (unsigned int*)(Bnxt + dstE1), 16, 0, 0);
      pvn = *(const bf16x8*)(pBase + kt + kg * 8);
      qvn = *(const bf16x8*)(qBase + kt + kg * 8);
    }
    // silu -> A fragment (row = l15's edge, k = t*32 + kg*8 + j)
    const int k0 = t * 32 + kg * 8;
    f32x4 wr0 = *(const f32x4*)&wgt[k0],       wr1 = *(const f32x4*)&wgt[k0 + 4];
    f32x4 wd0 = *(const f32x4*)&wgt[256 + k0], wd1 = *(const f32x4*)&wgt[256 + k0 + 4];
    bf16x8 af;
#pragma unroll
    for (int j = 0; j < 4; j++)
      af[j] = (__bf16)silu_f((float)pvc[j] + (float)qvc[j] + rad * wr0[j] + dd0 * wd0[j]);
#pragma unroll
    for (int j = 0; j < 4; j++)
      af[4 + j] = (__bf16)silu_f((float)pvc[4 + j] + (float)qvc[4 + j] + rad * wr1[j] + dd0 * wd1[j]);
    // 16 MFMAs: all 256 output cols
    __builtin_amdgcn_s_setprio(1);
#pragma unroll
    for (int fn = 0; fn < 16; fn++) {
      int n = fn * 16 + l15;
      bf16x8 bf = *(const bf16x8*)&Bcur[n * 32 + ((kg ^ ((n >> 1) & 3)) << 3)];
      acc[fn] = __builtin_amdgcn_mfma_f32_16x16x32_bf16(af, bf, acc[fn], 0, 0, 0);
    }
    __builtin_amdgcn_s_setprio(0);
    if (t < 7) { pvc = pvn; qvc = qvn; }
    __syncthreads();   // drains DMA (vmcnt) + orders buffer swap
  }

  // ---- epilogue ----
  if (EPI == 0) {
    // per-wave LDS restage (2 passes x 8 rows) -> coalesced 16B row stores
    __bf16* ep = (__bf16*)(smem + 4096 + w * 4224);  // [8][264]
#pragma unroll
    for (int p = 0; p < 2; p++) {
      if ((kg >> 1) == p) {
        int rl = (kg & 1) * 4;
#pragma unroll
        for (int fn = 0; fn < 16; fn++) {
          int col = fn * 16 + l15;
          float bv = wgt[512 + col];
#pragma unroll
          for (int j = 0; j < 4; j++)
            ep[(rl + j) * 264 + col] = (__bf16)silu_f(acc[fn][j] + bv);
        }
      }
      __syncthreads();
#pragma unroll
      for (int i = 0; i < 4; i++) {
        int r = i * 2 + (lane >> 5);
        int g = lane & 31;
        uint4 v = *(const uint4*)&ep[r * 264 + g * 8];
        *(uint4*)(m2p + ((size_t)(R0 + w * 16 + p * 8 + r)) * 256 + g * 8) = v;
      }
      __syncthreads();
    }
  } else {
    float s[4] = {0.f, 0.f, 0.f, 0.f};
#pragma unroll
    for (int fn = 0; fn < 16; fn++) {
      int col = fn * 16 + l15;
      float bv = wgt[512 + col], wv = wgt[768 + col];
#pragma unroll
      for (int j = 0; j < 4; j++)
        s[j] += silu_f(acc[fn][j] + bv) * wv;
    }
#pragma unroll
    for (int off = 1; off < 16; off <<= 1)
#pragma unroll
      for (int j = 0; j < 4; j++)
        s[j] += __shfl_xor(s[j], off, 64);
    __syncthreads();
    if (l15 == 0) {
#pragma unroll
      for (int j = 0; j < 4; j++)
        reds[w * 16 + kg * 4 + j] = s[j];
    }
    __syncthreads();
    if (tid < 128) {
      float sv = reds[tid];
      size_t i = (size_t)R0 + tid;
      transp[i * 3 + 0] = cdp[i * 3 + 0] * sv;
      transp[i * 3 + 1] = cdp[i * 3 + 1] * sv;
      transp[i * 3 + 2] = cdp[i * 3 + 2] * sv;
    }
  }
}

// ---------------- 64x64 MFMA GEMM, 2-phase double-buffered ----------------
// C = epi(A[M,K] @ Bt[N,K]^T + bias).
// SPLIT=1: logical K=512, A-rows = [A(256) || A2(256)], both row-stride 256.
// EPI: 1 silu->bf16, 2 residual f32+=v & bf16 out, 4 plain bf16 (no bias), 5 bias+bf16
template <int EPI, int SPLIT>
__global__ __launch_bounds__(256) void k_gemm64(const __bf16* __restrict__ A, const __bf16* __restrict__ A2,
                                                const __bf16* __restrict__ Bt,
                                                const float* __restrict__ bias, __bf16* __restrict__ outb,
                                                float* __restrict__ outf, int M, int N, int K) {
  constexpr int BM = 64, BN = 64, BK = 64;
  __shared__ __bf16 As[2][BM * BK];
  __shared__ __bf16 Bs[2][BN * BK];
  const int tid = threadIdx.x;
  const int lane = tid & 63;
  const int wave = tid >> 6;
  const int wm = wave >> 1, wn = wave & 1;   // wave tile 32x32
  const size_t m0 = (size_t)blockIdx.x * BM;
  const size_t n0 = (size_t)blockIdx.y * BN;
  const int r0 = tid >> 3, g0 = tid & 7;
  const int gs0 = (g0 ^ (r0 & 7)) << 3;
  const int Astride = SPLIT ? 256 : K;

  f32x4 acc[2][2] = {};
  const int NT = K >> 6;

  {  // prologue: tile 0 (always from A)
    uint4 a0 = *(const uint4*)(A + (m0 + r0) * Astride + g0 * 8);
    uint4 a1 = *(const uint4*)(A + (m0 + r0 + 32) * Astride + g0 * 8);
    uint4 b0 = *(const uint4*)(Bt + (n0 + r0) * K + g0 * 8);
    uint4 b1 = *(const uint4*)(Bt + (n0 + r0 + 32) * K + g0 * 8);
    *(uint4*)&As[0][r0 * BK + gs0] = a0;
    *(uint4*)&As[0][(r0 + 32) * BK + gs0] = a1;
    *(uint4*)&Bs[0][r0 * BK + gs0] = b0;
    *(uint4*)&Bs[0][(r0 + 32) * BK + gs0] = b1;
  }
  __syncthreads();

  int buf = 0;
  for (int t = 0; t < NT; ++t) {
    const bool has = (t + 1 < NT);
    uint4 a0, a1, b0, b1;
    if (has) {
      int kt = (t + 1) << 6;
      const __bf16* Ab;
      int ko;
      if (SPLIT) { Ab = (kt < 256) ? A : A2; ko = kt & 255; }
      else       { Ab = A; ko = kt; }
      a0 = *(const uint4*)(Ab + (m0 + r0) * Astride + ko + g0 * 8);
      a1 = *(const uint4*)(Ab + (m0 + r0 + 32) * Astride + ko + g0 * 8);
      b0 = *(const uint4*)(Bt + (n0 + r0) * K + kt + g0 * 8);
      b1 = *(const uint4*)(Bt + (n0 + r0 + 32) * K + kt + g0 * 8);
    }
#pragma unroll
    for (int ks = 0; ks < BK; ks += 32) {
      const int kg = (ks >> 3) + (lane >> 4);
      bf16x8 af[2], bfv[2];
#pragma unroll
      for (int fm = 0; fm < 2; fm++) {
        int r = wm * 32 + fm * 16 + (lane & 15);
        af[fm] = *(const bf16x8*)&As[buf][r * BK + ((kg ^ (r & 7)) << 3)];
      }
#pragma unroll
      for (int fn = 0; fn < 2; fn++) {
        int r = wn * 32 + fn * 16 + (lane & 15);
        bfv[fn] = *(const bf16x8*)&Bs[buf][r * BK + ((kg ^ (r & 7)) << 3)];
      }
#pragma unroll
      for (int fm = 0; fm < 2; fm++)
#pragma unroll
        for (int fn = 0; fn < 2; fn++)
          acc[fm][fn] = __builtin_amdgcn_mfma_f32_16x16x32_bf16(af[fm], bfv[fn], acc[fm][fn], 0, 0, 0);
    }
    if (has) {
      *(uint4*)&As[buf ^ 1][r0 * BK + gs0] = a0;
      *(uint4*)&As[buf ^ 1][(r0 + 32) * BK + gs0] = a1;
      *(uint4*)&Bs[buf ^ 1][r0 * BK + gs0] = b0;
      *(uint4*)&Bs[buf ^ 1][(r0 + 32) * BK + gs0] = b1;
    }
    __syncthreads();
    buf ^= 1;
  }

#pragma unroll
  for (int fm = 0; fm < 2; fm++) {
#pragma unroll
    for (int fn = 0; fn < 2; fn++) {
      const size_t col = n0 + wn * 32 + fn * 16 + (lane & 15);
      float bv = (EPI == 4) ? 0.f : bias[col];
#pragma unroll
      for (int j = 0; j < 4; j++) {
        size_t row = m0 + wm * 32 + fm * 16 + ((lane >> 4) << 2) + j;
        size_t idx = row * (size_t)N + col;
        float v = acc[fm][fn][j] + bv;
        if (EPI == 1) {
          outb[idx] = (__bf16)silu_f(v);
        } else if (EPI == 2) {
          float nh = outf[idx] + v;
          outf[idx] = nh;
          outb[idx] = (__bf16)nh;
        } else {
          outb[idx] = (__bf16)v;
        }
      }
    }
  }
}

// ---------------- host ----------------
extern "C" void kernel_launch(void* const* d_in, const int* in_sizes, int n_in,
                              void* d_out, int out_size, void* d_ws, size_t ws_size,
                              hipStream_t stream) {
  const float* h_in    = (const float*)d_in[0];
  const float* x_in    = (const float*)d_in[1];
  const int*   ei      = (const int*)d_in[2];
  const float* emb_w   = (const float*)d_in[3];
  const float* emb_b   = (const float*)d_in[4];
  const float* out_w   = (const float*)d_in[5];
  const float* out_b   = (const float*)d_in[6];
  const float* edge_w1 = (const float*)d_in[7];
  const float* edge_b1 = (const float*)d_in[8];
  const float* edge_w2 = (const float*)d_in[9];
  const float* edge_b2 = (const float*)d_in[10];
  const float* node_w1 = (const float*)d_in[11];
  const float* node_b1 = (const float*)d_in[12];
  const float* node_w2 = (const float*)d_in[13];
  const float* node_b2 = (const float*)d_in[14];
  const float* coord_w1 = (const float*)d_in[15];
  const float* coord_b1 = (const float*)d_in[16];
  const float* coord_w2 = (const float*)d_in[17];
  const float* coord_b2 = (const float*)d_in[18];
  const float* coord_w3 = (const float*)d_in[19];

  char* p = (char*)d_ws;
  auto alloc = [&](size_t bytes) -> void* {
    void* r = (void*)p;
    p += (bytes + 255) & ~(size_t)255;
    return r;
  };
  __bf16* e1T  = (__bf16*)alloc((size_t)6 * 512 * 256 * 2);
  __bf16* e2T  = (__bf16*)alloc((size_t)6 * 256 * 256 * 2);
  __bf16* n1T  = (__bf16*)alloc((size_t)6 * 256 * 512 * 2);
  __bf16* n2T  = (__bf16*)alloc((size_t)6 * 256 * 256 * 2);
  __bf16* c1T  = (__bf16*)alloc((size_t)3 * 512 * 256 * 2);
  __bf16* c2T  = (__bf16*)alloc((size_t)3 * 256 * 256 * 2);
  __bf16* h16  = (__bf16*)alloc((size_t)NN * HD * 2);
  __bf16* PQ16 = (__bf16*)alloc((size_t)NN * 512 * 2);
  __bf16* m2p  = (__bf16*)alloc((size_t)NE * HD * 2);
  __bf16* agg16 = (__bf16*)alloc((size_t)NN * HD * 2);
  __bf16* u    = (__bf16*)alloc((size_t)NN * HD * 2);
  float* hf    = (float*)alloc((size_t)NN * HD * 4);
  float* xc    = (float*)alloc((size_t)NN * 3 * 4);
  float* d0p   = (float*)alloc((size_t)NE * 4);
  float* radp  = (float*)alloc((size_t)NE * 4);
  float* cdp   = (float*)alloc((size_t)NE * 3 * 4);
  float* transp = (float*)alloc((size_t)NE * 3 * 4);
  float* bias512 = (float*)alloc((size_t)9 * 512 * 4);
  int* cnt     = (int*)alloc((size_t)NN * 4);
  int* offs    = (int*)alloc((size_t)(NN + 1) * 4);
  int* cursor  = (int*)alloc((size_t)NN * 4);
  int* elist   = (int*)alloc((size_t)NE * 4);
  int* rowp    = (int*)alloc((size_t)NE * 4);
  int* colp    = (int*)alloc((size_t)NE * 4);

  TJobs jobs;
  int nj = 0;
  for (int gi = 0; gi < 6; gi++) {
    jobs.j[nj++] = { edge_w1 + (size_t)gi * 514 * 256,             e1T + (size_t)gi * 512 * 256,             256, 256 };
    jobs.j[nj++] = { edge_w1 + (size_t)gi * 514 * 256 + 256 * 256, e1T + (size_t)gi * 512 * 256 + 256 * 256, 256, 256 };
    jobs.j[nj++] = { edge_w2 + (size_t)gi * 256 * 256,             e2T + (size_t)gi * 256 * 256,             256, 256 };
    jobs.j[nj++] = { node_w1 + (size_t)gi * 512 * 256,             n1T + (size_t)gi * 256 * 512,             512, 256 };
    jobs.j[nj++] = { node_w2 + (size_t)gi * 256 * 256,             n2T + (size_t)gi * 256 * 256,             256, 256 };
  }
  for (int b = 0; b < 3; b++) {
    jobs.j[nj++] = { coord_w1 + (size_t)b * 514 * 256,             c1T + (size_t)b * 512 * 256,              256, 256 };
    jobs.j[nj++] = { coord_w1 + (size_t)b * 514 * 256 + 256 * 256, c1T + (size_t)b * 512 * 256 + 256 * 256,  256, 256 };
    jobs.j[nj++] = { coord_w2 + (size_t)b * 256 * 256,             c2T + (size_t)b * 256 * 256,              256, 256 };
  }

  hipMemsetAsync(cnt, 0, (size_t)NN * 4, stream);
  k_transpose<<<dim3(16, 8, 39), 256, 0, stream>>>(jobs);
  k_hist<<<NE / 256, 256, 0, stream>>>(ei, cnt);
  k_scan<<<1, 1024, 0, stream>>>(cnt, offs, cursor);
  k_scatter<<<NE / 256, 256, 0, stream>>>(ei, cursor, elist);
  k_csrinit<<<NE / 256, 256, 0, stream>>>(elist, ei, x_in, rowp, colp, d0p, xc);
  k_mkbias<<<18, 256, 0, stream>>>(edge_b1, coord_b1, bias512);
  k_embed<<<NN, 256, 0, stream>>>(h_in, emb_w, emb_b, hf, h16);

  int gi = 0;
  for (int b = 0; b < 3; b++) {
    k_geo<<<NE / 256, 256, 0, stream>>>(rowp, colp, xc, radp, cdp);
    for (int s = 0; s < 2; s++, gi++) {
      const float* w1 = edge_w1 + (size_t)gi * 514 * 256;
      // PQ = h @ [W1a|W1b] + [b1|0]  -> bf16
      k_gemm64<5, 0><<<dim3(64, 8), 256, 0, stream>>>(
          h16, nullptr, e1T + (size_t)gi * 512 * 256, bias512 + gi * 512, PQ16, nullptr, NN, 512, 256);
      k_edgeblk<0><<<NE / 128, 512, 0, stream>>>(
          PQ16, rowp, colp, radp, d0p, w1 + 512 * 256, w1 + 513 * 256,
          e2T + (size_t)gi * 256 * 256, edge_b2 + gi * 256, m2p, nullptr, nullptr, nullptr);
      k_segsum<<<NN, 256, 0, stream>>>(m2p, offs, agg16);
      k_gemm64<1, 1><<<dim3(64, 4), 256, 0, stream>>>(
          h16, agg16, n1T + (size_t)gi * 256 * 512, node_b1 + gi * 256, u, nullptr, NN, 256, 512);
      k_gemm64<2, 0><<<dim3(64, 4), 256, 0, stream>>>(
          u, nullptr, n2T + (size_t)gi * 256 * 256, node_b2 + gi * 256, h16, hf, NN, 256, 256);
    }
    const float* w1c = coord_w1 + (size_t)b * 514 * 256;
    k_gemm64<5, 0><<<dim3(64, 8), 256, 0, stream>>>(
        h16, nullptr, c1T + (size_t)b * 512 * 256, bias512 + (6 + b) * 512, PQ16, nullptr, NN, 512, 256);
    k_edgeblk<1><<<NE / 128, 512, 0, stream>>>(
        PQ16, rowp, colp, radp, d0p, w1c + 512 * 256, w1c + 513 * 256,
        c2T + (size_t)b * 256 * 256, coord_b2 + b * 256, nullptr,
        coord_w3 + (size_t)b * 256, cdp, transp);
    k_xupd<<<NN / 256, 256, 0, stream>>>(transp, offs, xc);
  }
  k_out<<<256 + 48, 256, 0, stream>>>(hf, out_w, out_b, xc, (float*)d_out);
}